// Round 4
// baseline (7400016.406 us; speedup 1.0000x reference)
//
#include <hip/hip_runtime.h>
#include <math.h>

#define LEAK   0.3f
#define ONEML  0.7f

typedef unsigned short u16;
typedef unsigned int   u32;
typedef unsigned long long u64;
typedef __attribute__((ext_vector_type(4))) float f32x4;
typedef __attribute__((ext_vector_type(8))) short s16x8;

constexpr int B = 256, T = 1000, F = 64, H = 1024, O = 10, NTAIL = 8;
constexpr int TSTART  = T - NTAIL;   // 992
constexpr int KS      = 34;          // 2 k-steps (W_in, K=64) + 32 k-steps (W_r, K=1024)
constexpr int PSTRIDE = 1096;        // LDS panel row stride: 1088 + 8 pad

// workspace layout (bytes)
constexpr size_t OFF_PACKED = 0;          // 64*34*64*8 u16  = 2,228,224 B
constexpr size_t OFF_HGL    = 0x240000;   // 2*16*16*1024 u16 = 1,048,576 B (double-buffered h exchange)
constexpr size_t OFF_FLAGS  = 0x340000;   // 4096 u32: [w*16]=step flag, [w*16+8]=xcc-id handshake
constexpr size_t OFF_FEATS  = 0x344000;   // 256*8192 f32 = 8 MB

template<bool V> struct BoolC { static constexpr bool value = V; };

__device__ __forceinline__ u16 f2bf(float f) {
  union { float f; u32 u; } v; v.f = f;
  u32 r = v.u + 0x7fffu + ((v.u >> 16) & 1u);   // RNE
  return (u16)(r >> 16);
}

// fast tanh: clamp(+-9) -> exp2 -> rcp. |rel err| ~1e-7, far below bf16 budget.
__device__ __forceinline__ float ftanh(float s) {
  const float sc = fminf(fmaxf(s, -9.0f), 9.0f);
  const float e2 = __builtin_amdgcn_exp2f(sc * 2.8853900817779268f);  // exp(2s)
  return 1.0f - 2.0f * __builtin_amdgcn_rcpf(e2 + 1.0f);
}

// Pack [W_in; W_r] columns into MFMA B-fragment order:
// packed[nt(64)][ks(34)][lane(64)][j(8)] = W[k = base(ks) + 8*(lane>>4) + j][n = nt*16 + (lane&15)]
// A-side LDS reads use the SAME (lane,j)->k map, so any HW k-slot permutation cancels.
__global__ void esn_pack(const float* __restrict__ w_in, const float* __restrict__ w_r,
                         u16* __restrict__ packed) {
  int gid = blockIdx.x * 256 + threadIdx.x;
  if (gid >= 64 * KS * 64) return;
  int lane = gid & 63;
  int ks   = (gid >> 6) % KS;
  int nt   = gid / (KS * 64);
  int n    = nt * 16 + (lane & 15);
  int g    = lane >> 4;
  u16 v[8];
  #pragma unroll
  for (int jj = 0; jj < 8; ++jj) {
    int kk = 8 * g + jj;
    float w;
    if (ks < 2) w = w_in[(ks * 32 + kk) * H + n];
    else        w = w_r[((ks - 2) * 32 + kk) * H + n];
    v[jj] = f2bf(w);
  }
  u64* dst = (u64*)(packed + (size_t)gid * 8);
  dst[0] = ((const u64*)v)[0];
  dst[1] = ((const u64*)v)[1];
}

// 16 clusters (16 batch rows each) x 16 WGs (64-col slices), co-located per XCD via the
// (runtime-verified) bid%8 round-robin. FAST intra-XCD protocol:
//   writer: global_store sc0 (write-through to XCD L2) -> vmcnt(0) -> barrier -> flag store sc0
//   reader: poll { buffer_inv sc0 (L1-only inv); plain flag load } -> plain data loads from L2
// Round-3 lesson: sc0 on a *load* did NOT give L1-bypass (stale flag line spun the guard
// valve every step). The inv-inside-the-poll is stale-proof on the reader side; sc0 on
// stores pins the writer side at L2. Fallback (mapping mismatch): round-2 sc1/AGENT protocol.
__global__ __launch_bounds__(256, 1) void esn_recur(const float* __restrict__ x,
    const u16* __restrict__ packed, u16* __restrict__ hgl,
    u32* __restrict__ flags, float* __restrict__ feats) {
  __shared__ u16 panel[2][16][PSTRIDE];   // [dbuf][batch row][k-col: 0..63 = x_t, 64..1087 = h]
  __shared__ u16 forcepad[6144];          // pad LDS >80KB -> exactly 1 WG/CU

  const int tid  = threadIdx.x;
  const int lane = tid & 63, wv = tid >> 6;
  const int bid  = blockIdx.x;
  const int kk   = bid >> 3;                    // 0..31 within an XCD (bid%8 = XCD)
  const int ci   = (bid & 7) * 2 + (kk >> 4);   // cluster = batch group (XCD-co-located)
  const int cj   = kk & 15;                     // column group within cluster
  const int g    = lane >> 4, m16 = lane & 15;
  const int nt   = cj * 4 + wv;           // this wave's 16-col tile
  const int cc   = nt * 16 + m16;         // H-column this lane owns in D
  const int bbase = ci * 16;
  const bool ownCols = ((tid >> 4) == cj);

  // ---- runtime XCD co-location handshake (once) ----
  u32 myxcc;
  asm volatile("s_getreg_b32 %0, hwreg(HW_REG_XCC_ID)" : "=s"(myxcc));
  if (tid == 0)
    __hip_atomic_store(&flags[bid * 16 + 8], (myxcc & 0xffu) | 0x100u,
                       __ATOMIC_RELAXED, __HIP_MEMORY_SCOPE_AGENT);
  bool fast;
  {
    const int p = lane & 15;
    const int pbid = (ci >> 1) + 8 * (((ci & 1) << 4) + p);  // peer p's bid
    u32 v = 0; int guard = 0; bool ok = true;
    for (;;) {
      v = __hip_atomic_load(&flags[pbid * 16 + 8], __ATOMIC_RELAXED, __HIP_MEMORY_SCOPE_AGENT);
      if (__all((int)(v >= 0x100u))) break;
      if (++guard > (1 << 20)) { ok = false; break; }
    }
    fast = ok && __all((int)((v & 0xffu) == (myxcc & 0xffu)));
  }

  // W fragments: resident in VGPRs for the whole kernel (34 x 4 VGPR = 136)
  s16x8 bfrag[KS];
  #pragma unroll
  for (int ks = 0; ks < KS; ++ks)
    bfrag[ks] = *(const s16x8*)(packed + (((size_t)nt * KS + ks) * 64 + lane) * 8);

  auto loop = [&](auto FC) {
    constexpr bool FAST = decltype(FC)::value;
    float hreg[4] = {0.f, 0.f, 0.f, 0.f};

    for (int t = 0; t < T; ++t) {
      const int buf = t & 1;
      const int nb  = buf ^ 1;

      // stage x_t tile (16 rows x 64 cols, f32 -> bf16) — independent of peers, before poll
      {
        const int r = tid >> 4;
        const int c = (tid & 15) * 4;
        const float4 v = *(const float4*)(x + (((size_t)(bbase + r)) * T + t) * (size_t)F + c);
        u16 o[4] = { f2bf(v.x), f2bf(v.y), f2bf(v.z), f2bf(v.w) };
        *(u64*)&panel[buf][r][c] = *(const u64*)o;
      }

      // wait until all 16 peer WGs of this cluster published h_{t-1}
      if (t > 0) {
        const u32 target = (u32)t;
        int guard = 0;
        if constexpr (FAST) {
          u32* fp = &flags[(ci * 16 + (lane & 15)) * 16];
          for (;;) {
            asm volatile("buffer_inv sc0" ::: "memory");   // L1-only invalidate
            u32 fv = target;
            if (lane < 16) {
              u32 tmp;
              asm volatile("global_load_dword %0, %1, off\n\ts_waitcnt vmcnt(0)"
                           : "=v"(tmp) : "v"(fp) : "memory");
              fv = tmp;
            }
            if (__all((int)(fv >= target))) break;
            if (++guard > (1 << 16)) break;   // safety valve: wrong answer beats a hang
          }
        } else {
          const int p = lane & 15;
          for (;;) {
            u32 fv = __hip_atomic_load(&flags[(ci * 16 + p) * 16],
                                       __ATOMIC_RELAXED, __HIP_MEMORY_SCOPE_AGENT);
            if (__all((int)(fv >= target))) break;
            if (++guard > (1 << 16)) break;
          }
          asm volatile("" ::: "memory");
        }
      }

      // stage h panel. Own 64 columns were written into panel[buf] at step t-1 — skip.
      if (t == 0) {
        #pragma unroll
        for (int it = 0; it < 16; ++it)
          *(u64*)&panel[buf][it][64 + tid * 4] = 0ULL;
      } else if (!ownCols) {
        const int pb = (t + 1) & 1;          // (t-1)&1
        u64 vb[16];
        if constexpr (FAST) {
          #pragma unroll
          for (int it = 0; it < 16; ++it)
            vb[it] = *(const u64*)(hgl + ((((size_t)pb * 16 + ci) * 16 + it) * H + tid * 4));
        } else {
          #pragma unroll
          for (int it = 0; it < 16; ++it)
            vb[it] = __hip_atomic_load(
                (const u64*)(hgl + ((((size_t)pb * 16 + ci) * 16 + it) * H + tid * 4)),
                __ATOMIC_RELAXED, __HIP_MEMORY_SCOPE_AGENT);
        }
        #pragma unroll
        for (int it = 0; it < 16; ++it)
          *(u64*)&panel[buf][it][64 + tid * 4] = vb[it];
      }
      __syncthreads();

      // K loop: 34 k-steps of 32 (x@W_in then h@W_r), two interleaved acc chains
      f32x4 acc0 = {0.f,0.f,0.f,0.f}, acc1 = {0.f,0.f,0.f,0.f};
      #pragma unroll
      for (int ks = 0; ks < KS; ++ks) {
        s16x8 a = *(const s16x8*)&panel[buf][m16][ks * 32 + g * 8];
        if (ks & 1) acc1 = __builtin_amdgcn_mfma_f32_16x16x32_bf16(a, bfrag[ks], acc1, 0, 0, 0);
        else        acc0 = __builtin_amdgcn_mfma_f32_16x16x32_bf16(a, bfrag[ks], acc0, 0, 0, 0);
      }

      // epilogue: lane owns rows 4g..4g+3 at col cc (D: col=lane&15, row=4*(lane>>4)+reg).
      // Write own tile into panel[nb] (next step's buffer) — the LDS transpose.
      #pragma unroll
      for (int r = 0; r < 4; ++r) {
        const float s  = acc0[r] + acc1[r];
        const float th = ftanh(s);
        const float hn = (t == 0) ? th : (ONEML * hreg[r] + LEAK * th);
        hreg[r] = hn;
        const int rr = g * 4 + r;
        panel[nb][rr][64 + cc] = f2bf(hn);
        if (t >= TSTART)
          feats[((size_t)(bbase + rr)) * (H * NTAIL) + (t - TSTART) * H + cc] = hn;
      }

      // own 16x64 tile: LDS -> global (each wave publishes its 16 columns)
      asm volatile("s_waitcnt lgkmcnt(0)" ::: "memory");
      {
        const int r  = lane >> 2;
        const int c4 = (lane & 3) * 4;
        const u64 v = *(const u64*)&panel[nb][r][64 + nt * 16 + c4];
        u64* gp = (u64*)(hgl + ((((size_t)buf * 16 + ci) * 16 + r) * H + nt * 16 + c4));
        if constexpr (FAST)
          asm volatile("global_store_dwordx2 %0, %1, off sc0" :: "v"(gp), "v"(v) : "memory");
        else
          __hip_atomic_store(gp, v, __ATOMIC_RELAXED, __HIP_MEMORY_SCOPE_AGENT);
      }

      // writer-side ordering: drain own stores (acked at L2), barrier, then flag
      asm volatile("s_waitcnt vmcnt(0)" ::: "memory");
      __syncthreads();
      if (tid == 0) {
        u32* fp2 = &flags[(ci * 16 + cj) * 16];
        const u32 val = (u32)(t + 1);
        if constexpr (FAST)
          asm volatile("global_store_dword %0, %1, off sc0" :: "v"(fp2), "v"(val) : "memory");
        else
          __hip_atomic_store(fp2, val, __ATOMIC_RELAXED, __HIP_MEMORY_SCOPE_AGENT);
      }
    }
  };

  if (fast) loop(BoolC<true>{});
  else      loop(BoolC<false>{});

  if (tid == 255) ((volatile u16*)forcepad)[0] = (u16)lane;  // keep pad alive
}

// out[b,o] = feats[b,:] . w_lin[o,:] + b_lin[o]
__global__ __launch_bounds__(256) void esn_out(const float* __restrict__ feats,
    const float* __restrict__ w_lin, const float* __restrict__ b_lin,
    float* __restrict__ out) {
  const int b = blockIdx.x;
  const int tid = threadIdx.x;
  const int lane = tid & 63, wv = tid >> 6;
  float p[O];
  #pragma unroll
  for (int o = 0; o < O; ++o) p[o] = 0.f;
  const float* fr = feats + (size_t)b * (H * NTAIL);
  for (int idx = tid; idx < H * NTAIL; idx += 256) {
    const float f = fr[idx];
    #pragma unroll
    for (int o = 0; o < O; ++o) p[o] += f * w_lin[o * (H * NTAIL) + idx];
  }
  __shared__ float red[O][4];
  #pragma unroll
  for (int o = 0; o < O; ++o) {
    float v = p[o];
    for (int off = 32; off > 0; off >>= 1) v += __shfl_down(v, off);
    if (lane == 0) red[o][wv] = v;
  }
  __syncthreads();
  if (tid < O)
    out[b * O + tid] = red[tid][0] + red[tid][1] + red[tid][2] + red[tid][3] + b_lin[tid];
}

extern "C" void kernel_launch(void* const* d_in, const int* in_sizes, int n_in,
                              void* d_out, int out_size, void* d_ws, size_t ws_size,
                              hipStream_t stream) {
  const float* x     = (const float*)d_in[0];
  const float* w_in  = (const float*)d_in[1];
  const float* w_r   = (const float*)d_in[2];
  const float* w_lin = (const float*)d_in[3];
  const float* b_lin = (const float*)d_in[4];
  char* ws = (char*)d_ws;
  u16* packed = (u16*)(ws + OFF_PACKED);
  u16* hgl    = (u16*)(ws + OFF_HGL);
  u32* flags  = (u32*)(ws + OFF_FLAGS);
  float* feats= (float*)(ws + OFF_FEATS);
  float* out  = (float*)d_out;

  hipMemsetAsync(flags, 0, 4096 * sizeof(u32), stream);   // flags + handshake start at 0
  esn_pack<<<(64 * KS * 64 + 255) / 256, 256, 0, stream>>>(w_in, w_r, packed);

  void* args[] = { (void*)&x, (void*)&packed, (void*)&hgl, (void*)&flags, (void*)&feats };
  hipLaunchCooperativeKernel((void*)esn_recur, dim3(256), dim3(256), args, 0, stream);

  esn_out<<<B, 256, 0, stream>>>(feats, w_lin, b_lin, out);
}

// Round 5
// 3267.448 us; speedup vs baseline: 2264.7697x; 2264.7697x over previous
//
#include <hip/hip_runtime.h>
#include <math.h>

#define LEAK   0.3f
#define ONEML  0.7f

typedef unsigned short u16;
typedef unsigned int   u32;
typedef unsigned long long u64;
typedef __attribute__((ext_vector_type(4))) float f32x4;
typedef __attribute__((ext_vector_type(8))) short s16x8;

constexpr int B = 256, T = 1000, F = 64, H = 1024, O = 10, NTAIL = 8;
constexpr int TSTART  = T - NTAIL;   // 992
constexpr int KS      = 34;          // 2 k-steps (W_in, K=64) + 32 k-steps (W_r, K=1024)
constexpr int PSTRIDE = 1096;        // LDS panel row stride: 1088 + 8 pad

// workspace layout (bytes)
constexpr size_t OFF_PACKED = 0;          // 64*34*64*8 u16  = 2,228,224 B
constexpr size_t OFF_HGL    = 0x240000;   // 2*16*16*1024 u16 = 1,048,576 B (double-buffered h exchange)
constexpr size_t OFF_FLAGS  = 0x340000;   // 16 clusters * 64 wave-flags, 4B stride (coalesced poll)
constexpr size_t OFF_FEATS  = 0x344000;   // 256*8192 f32 = 8 MB

__device__ __forceinline__ u16 f2bf(float f) {
  union { float f; u32 u; } v; v.f = f;
  u32 r = v.u + 0x7fffu + ((v.u >> 16) & 1u);   // RNE
  return (u16)(r >> 16);
}

// fast tanh: clamp(+-9) -> exp2 -> rcp. |rel err| ~1e-7, far below bf16 budget.
// (validated rounds 3/4: absmax identical to tanhf build)
__device__ __forceinline__ float ftanh(float s) {
  const float sc = fminf(fmaxf(s, -9.0f), 9.0f);
  const float e2 = __builtin_amdgcn_exp2f(sc * 2.8853900817779268f);  // exp(2s)
  return 1.0f - 2.0f * __builtin_amdgcn_rcpf(e2 + 1.0f);
}

// Pack [W_in; W_r] columns into MFMA B-fragment order:
// packed[nt(64)][ks(34)][lane(64)][j(8)] = W[k = base(ks) + 8*(lane>>4) + j][n = nt*16 + (lane&15)]
// A-side LDS reads use the SAME (lane,j)->k map, so any HW k-slot permutation cancels.
__global__ void esn_pack(const float* __restrict__ w_in, const float* __restrict__ w_r,
                         u16* __restrict__ packed) {
  int gid = blockIdx.x * 256 + threadIdx.x;
  if (gid >= 64 * KS * 64) return;
  int lane = gid & 63;
  int ks   = (gid >> 6) % KS;
  int nt   = gid / (KS * 64);
  int n    = nt * 16 + (lane & 15);
  int g    = lane >> 4;
  u16 v[8];
  #pragma unroll
  for (int jj = 0; jj < 8; ++jj) {
    int kk = 8 * g + jj;
    float w;
    if (ks < 2) w = w_in[(ks * 32 + kk) * H + n];
    else        w = w_r[((ks - 2) * 32 + kk) * H + n];
    v[jj] = f2bf(w);
  }
  u64* dst = (u64*)(packed + (size_t)gid * 8);
  dst[0] = ((const u64*)v)[0];
  dst[1] = ((const u64*)v)[1];
}

// 16 independent clusters (batch groups of 16 rows) x 16 WGs (64-col slices).
// Proven L3 (sc1/AGENT) exchange protocol from round 2, with two serialization cuts:
//  - per-WAVE flags (vmcnt drain is per-wave; no end-of-step __syncthreads, no
//    barrier-to-flag hop). Flag(t+1) also releases the wave's h_{t-1} reads, so the
//    double-buffered hgl slot is never overwritten while a peer still reads it.
//  - flags packed at 4B stride: lane l polls flag l -> one coalesced 256B load/iter.
// Single __syncthreads per step (pre-MFMA); all LDS writes across skewed waves are
// address-disjoint (x region / own-64-col region / peer-col staging).
__global__ __launch_bounds__(256, 1) void esn_recur(const float* __restrict__ x,
    const u16* __restrict__ packed, u16* __restrict__ hgl,
    u32* __restrict__ flags, float* __restrict__ feats) {
  __shared__ u16 panel[2][16][PSTRIDE];   // [dbuf][batch row][k-col: 0..63 = x_t, 64..1087 = h]
  __shared__ u16 forcepad[6144];          // pad LDS >80KB -> exactly 1 WG/CU

  const int tid  = threadIdx.x;
  const int lane = tid & 63, wv = tid >> 6;
  const int ci   = blockIdx.x >> 4;       // cluster = batch group
  const int cj   = blockIdx.x & 15;       // column group
  const int g    = lane >> 4, m16 = lane & 15;
  const int nt   = cj * 4 + wv;           // this wave's 16-col tile == wave id in cluster (0..63)
  const int cc   = nt * 16 + m16;         // H-column this lane owns in D
  const int bbase = ci * 16;
  const bool ownCols = ((tid >> 4) == cj); // this thread's staging columns are our own WG's 64

  // W fragments: resident in VGPRs for the whole kernel (34 x 4 VGPR = 136)
  s16x8 bfrag[KS];
  #pragma unroll
  for (int ks = 0; ks < KS; ++ks)
    bfrag[ks] = *(const s16x8*)(packed + (((size_t)nt * KS + ks) * 64 + lane) * 8);

  // exact f32 carried state for the 4 (row,col) positions this lane owns
  float hreg[4] = {0.f, 0.f, 0.f, 0.f};

  for (int t = 0; t < T; ++t) {
    const int buf = t & 1;
    const int nb  = buf ^ 1;

    // stage x_t tile (16 rows x 64 cols, f32 -> bf16) — independent of peers, before poll
    {
      const int r = tid >> 4;
      const int c = (tid & 15) * 4;
      const float4 v = *(const float4*)(x + (((size_t)(bbase + r)) * T + t) * (size_t)F + c);
      u16 o[4] = { f2bf(v.x), f2bf(v.y), f2bf(v.z), f2bf(v.w) };
      *(u64*)&panel[buf][r][c] = *(const u64*)o;
    }

    // wait until all 64 peer WAVES of this cluster published h_{t-1}
    // (lane l polls flag l: 64 x 4B contiguous -> one coalesced load per iteration)
    if (t > 0) {
      const u32 target = (u32)t;
      u32* fp = &flags[ci * 64 + lane];
      int guard = 0;
      for (;;) {
        u32 fv = __hip_atomic_load(fp, __ATOMIC_RELAXED, __HIP_MEMORY_SCOPE_AGENT);
        if (__all((int)(fv >= target))) break;
        if (++guard > (1 << 16)) break;   // safety valve: wrong answer beats a hang
      }
      asm volatile("" ::: "memory");      // keep data loads below the poll
    }

    // stage h panel from L3-coherent global. Own 64 columns were already written into
    // panel[buf] by our epilogue at step t-1 — skip them (t>0).
    if (t == 0) {
      #pragma unroll
      for (int it = 0; it < 16; ++it)
        *(u64*)&panel[buf][it][64 + tid * 4] = 0ULL;
    } else if (!ownCols) {
      const int pb = (t + 1) & 1;          // (t-1)&1
      u64 vb[16];
      #pragma unroll
      for (int it = 0; it < 16; ++it)
        vb[it] = __hip_atomic_load(
            (const u64*)(hgl + ((((size_t)pb * 16 + ci) * 16 + it) * H + tid * 4)),
            __ATOMIC_RELAXED, __HIP_MEMORY_SCOPE_AGENT);
      #pragma unroll
      for (int it = 0; it < 16; ++it)
        *(u64*)&panel[buf][it][64 + tid * 4] = vb[it];
    }
    __syncthreads();   // the ONLY barrier per step: staging + prior epilogue all visible

    // K loop: 34 k-steps of 32 (x@W_in then h@W_r), two interleaved acc chains
    f32x4 acc0 = {0.f,0.f,0.f,0.f}, acc1 = {0.f,0.f,0.f,0.f};
    #pragma unroll
    for (int ks = 0; ks < KS; ++ks) {
      s16x8 a = *(const s16x8*)&panel[buf][m16][ks * 32 + g * 8];
      if (ks & 1) acc1 = __builtin_amdgcn_mfma_f32_16x16x32_bf16(a, bfrag[ks], acc1, 0, 0, 0);
      else        acc0 = __builtin_amdgcn_mfma_f32_16x16x32_bf16(a, bfrag[ks], acc0, 0, 0, 0);
    }

    // epilogue: lane owns rows 4g..4g+3 at col cc (D: col=lane&15, row=4*(lane>>4)+reg).
    // Write own tile into panel[nb] (next step's buffer) — the LDS transpose.
    #pragma unroll
    for (int r = 0; r < 4; ++r) {
      const float s  = acc0[r] + acc1[r];
      const float th = ftanh(s);
      const float hn = (t == 0) ? th : (ONEML * hreg[r] + LEAK * th);
      hreg[r] = hn;
      const int rr = g * 4 + r;
      panel[nb][rr][64 + cc] = f2bf(hn);
      if (t >= TSTART)
        feats[((size_t)(bbase + rr)) * (H * NTAIL) + (t - TSTART) * H + cc] = hn;
    }

    // own 16x16 tile: LDS -> global (wave publishes the 16 columns it computed)
    asm volatile("s_waitcnt lgkmcnt(0)" ::: "memory");
    {
      const int r  = lane >> 2;
      const int c4 = (lane & 3) * 4;
      const u64 v = *(const u64*)&panel[nb][r][64 + nt * 16 + c4];
      __hip_atomic_store(
          (u64*)(hgl + ((((size_t)buf * 16 + ci) * 16 + r) * H + nt * 16 + c4)),
          v, __ATOMIC_RELAXED, __HIP_MEMORY_SCOPE_AGENT);
    }

    // per-wave release: drain own stores (and own h_{t-1} loads), then own flag.
    // No barrier — vmcnt is a per-wave counter.
    asm volatile("s_waitcnt vmcnt(0)" ::: "memory");
    if (lane == 0)
      __hip_atomic_store(&flags[ci * 64 + nt], (u32)(t + 1),
                         __ATOMIC_RELAXED, __HIP_MEMORY_SCOPE_AGENT);
  }
  if (tid == 255) ((volatile u16*)forcepad)[0] = (u16)lane;  // keep pad alive
}

// out[b,o] = feats[b,:] . w_lin[o,:] + b_lin[o]
__global__ __launch_bounds__(256) void esn_out(const float* __restrict__ feats,
    const float* __restrict__ w_lin, const float* __restrict__ b_lin,
    float* __restrict__ out) {
  const int b = blockIdx.x;
  const int tid = threadIdx.x;
  const int lane = tid & 63, wv = tid >> 6;
  float p[O];
  #pragma unroll
  for (int o = 0; o < O; ++o) p[o] = 0.f;
  const float* fr = feats + (size_t)b * (H * NTAIL);
  for (int idx = tid; idx < H * NTAIL; idx += 256) {
    const float f = fr[idx];
    #pragma unroll
    for (int o = 0; o < O; ++o) p[o] += f * w_lin[o * (H * NTAIL) + idx];
  }
  __shared__ float red[O][4];
  #pragma unroll
  for (int o = 0; o < O; ++o) {
    float v = p[o];
    for (int off = 32; off > 0; off >>= 1) v += __shfl_down(v, off);
    if (lane == 0) red[o][wv] = v;
  }
  __syncthreads();
  if (tid < O)
    out[b * O + tid] = red[tid][0] + red[tid][1] + red[tid][2] + red[tid][3] + b_lin[tid];
}

extern "C" void kernel_launch(void* const* d_in, const int* in_sizes, int n_in,
                              void* d_out, int out_size, void* d_ws, size_t ws_size,
                              hipStream_t stream) {
  const float* x     = (const float*)d_in[0];
  const float* w_in  = (const float*)d_in[1];
  const float* w_r   = (const float*)d_in[2];
  const float* w_lin = (const float*)d_in[3];
  const float* b_lin = (const float*)d_in[4];
  char* ws = (char*)d_ws;
  u16* packed = (u16*)(ws + OFF_PACKED);
  u16* hgl    = (u16*)(ws + OFF_HGL);
  u32* flags  = (u32*)(ws + OFF_FLAGS);
  float* feats= (float*)(ws + OFF_FEATS);
  float* out  = (float*)d_out;

  hipMemsetAsync(flags, 0, 4096 * sizeof(u32), stream);   // monotonic flags start at 0 each call
  esn_pack<<<(64 * KS * 64 + 255) / 256, 256, 0, stream>>>(w_in, w_r, packed);

  void* args[] = { (void*)&x, (void*)&packed, (void*)&hgl, (void*)&flags, (void*)&feats };
  hipLaunchCooperativeKernel((void*)esn_recur, dim3(256), dim3(256), args, 0, stream);

  esn_out<<<B, 256, 0, stream>>>(feats, w_lin, b_lin, out);
}